// Round 1
// baseline (1592.925 us; speedup 1.0000x reference)
//
#include <hip/hip_runtime.h>

#define N_NODES 100000
#define NREL 6
#define NEDGE 400000
#define FDIM 128
#define HID 128

constexpr int RN = NREL * N_NODES;   // 600000
constexpr int RE = NREL * NEDGE;     // 2400000
constexpr int NB_SCAN = (N_NODES + 1023) / 1024;  // 98

typedef __attribute__((ext_vector_type(8))) short short8;
typedef __attribute__((ext_vector_type(4))) float f32x4;

__device__ __forceinline__ unsigned short f2bf(float f) {
  union { float f; unsigned int u; } v; v.f = f;
  unsigned int u = v.u;
  unsigned int r = (u + 0x7FFFu + ((u >> 16) & 1u)) >> 16;
  return (unsigned short)r;
}
__device__ __forceinline__ float bf2f(unsigned int bits) {
  union { unsigned int u; float f; } v; v.u = bits << 16;
  return v.f;
}

// ---------------- zero workspace ----------------
__global__ void k_zero(unsigned int* __restrict__ p, int nwords) {
  int id = blockIdx.x * blockDim.x + threadIdx.x;
  if (id < nwords) p[id] = 0u;
}

// ---------------- degree histograms ----------------
__global__ void k_deg(const int* __restrict__ src, const int* __restrict__ dst,
                      int* __restrict__ deg_out, int* __restrict__ deg_in) {
  int id = blockIdx.x * 256 + threadIdx.x;
  if (id < RE) {
    int r = id / NEDGE;
    atomicAdd(&deg_out[r * N_NODES + src[id]], 1);
    atomicAdd(&deg_in[r * N_NODES + dst[id]], 1);
  }
}

// ---------------- norms ----------------
__global__ void k_norm(const int* __restrict__ deg_out, const int* __restrict__ deg_in,
                       float* __restrict__ norm_src, float* __restrict__ norm_dst) {
  int id = blockIdx.x * 256 + threadIdx.x;
  if (id < RN) {
    int dO = deg_out[id];
    int dI = deg_in[id];
    norm_src[id] = dO > 0 ? rsqrtf((float)dO) : 0.f;
    norm_dst[id] = dI > 0 ? rsqrtf((float)dI) : 0.f;
  }
}

// ---------------- W1 transpose+bf16 convert, bias sums ----------------
__global__ void k_wconv(const float* __restrict__ W1, const float* __restrict__ b1,
                        const float* __restrict__ b2,
                        unsigned short* __restrict__ W1T,
                        float* __restrict__ bias1, float* __restrict__ bias2) {
  int id = blockIdx.x * 256 + threadIdx.x;
  if (id < NREL * FDIM * HID) {
    int r = id >> 14;
    int rem = id & 16383;
    int j = rem >> 7;      // output feature
    int k = rem & 127;     // input feature
    W1T[id] = f2bf(W1[r * 16384 + k * 128 + j]);  // W1T[r][j][k] = W1[r][k][j]
  }
  if (id < HID) {
    float s1 = 0.f, s2 = 0.f;
    for (int r = 0; r < NREL; ++r) {
      s1 += b1[r * HID + id];
      s2 += b2[r * HID + id];
    }
    bias1[id] = s1;
    bias2[id] = s2;
  }
}

// ---------------- coef_r[src] += norm_dst_r[dst] ----------------
__global__ void k_coef(const int* __restrict__ src, const int* __restrict__ dst,
                       const float* __restrict__ norm_dst, float* __restrict__ coef) {
  int id = blockIdx.x * 256 + threadIdx.x;
  if (id < RE) {
    int r = id / NEDGE;
    atomicAdd(&coef[r * N_NODES + src[id]], norm_dst[r * N_NODES + dst[id]]);
  }
}

// ---------------- scan (3 stages) for CSR offsets ----------------
__global__ __launch_bounds__(1024) void k_scan1(const int* __restrict__ deg_in,
                                                int* __restrict__ csr_off,
                                                int* __restrict__ blockSums) {
  __shared__ int sh[1024];
  int r = blockIdx.x / NB_SCAN;
  int b = blockIdx.x % NB_SCAN;
  int t = threadIdx.x;
  int n = b * 1024 + t;
  int v = (n < N_NODES) ? deg_in[r * N_NODES + n] : 0;
  sh[t] = v;
  __syncthreads();
  int sum = v;
  for (int offi = 1; offi < 1024; offi <<= 1) {
    int y = (t >= offi) ? sh[t - offi] : 0;
    __syncthreads();
    sum += y;
    sh[t] = sum;
    __syncthreads();
  }
  if (n < N_NODES) csr_off[r * N_NODES + n] = sum - v;  // exclusive
  if (t == 1023) blockSums[blockIdx.x] = sum;
}

__global__ void k_scan2(int* __restrict__ blockSums) {
  int r = threadIdx.x;
  if (r < NREL) {
    int run = 0;
    for (int b = 0; b < NB_SCAN; ++b) {
      int t = blockSums[r * NB_SCAN + b];
      blockSums[r * NB_SCAN + b] = run;
      run += t;
    }
  }
}

__global__ void k_scan3(int* __restrict__ csr_off, const int* __restrict__ blockSums) {
  int id = blockIdx.x * 256 + threadIdx.x;
  if (id < RN) {
    int r = id / N_NODES;
    int n = id - r * N_NODES;
    csr_off[id] += blockSums[r * NB_SCAN + (n >> 10)];
  }
}

// ---------------- CSR fill ----------------
__global__ void k_fill(const int* __restrict__ src, const int* __restrict__ dst,
                       const int* __restrict__ csr_off, int* __restrict__ cursor,
                       int* __restrict__ csr_src) {
  int id = blockIdx.x * 256 + threadIdx.x;
  if (id < RE) {
    int r = id / NEDGE;
    int d = dst[id];
    int p = atomicAdd(&cursor[r * N_NODES + d], 1);
    csr_src[(size_t)r * NEDGE + csr_off[r * N_NODES + d] + p] = src[id];
  }
}

// ---------------- fused layer-1: aggregate + MFMA GEMM + relu -> h (bf16) ----------------
__global__ __launch_bounds__(256) void k_layer1(
    const float* __restrict__ x,
    const int* __restrict__ csr_src,
    const int* __restrict__ csr_off,
    const int* __restrict__ deg_in,
    const float* __restrict__ norm_src,
    const float* __restrict__ norm_dst,
    const unsigned short* __restrict__ W1T,  // [R][128][128] bf16, (out_feat, in_feat)
    const float* __restrict__ bias1,
    unsigned short* __restrict__ h)          // [N][128] bf16
{
  __shared__ unsigned short zA[64][136];   // +8 pad: breaks 256B-stride bank aliasing
  __shared__ unsigned short wT[128][136];
  const int tid = threadIdx.x;
  const int wave = tid >> 6;
  const int lane = tid & 63;
  const int nodeBase = blockIdx.x * 64;

  f32x4 acc[8];
#pragma unroll
  for (int t = 0; t < 8; ++t) acc[t] = (f32x4){0.f, 0.f, 0.f, 0.f};

  for (int r = 0; r < NREL; ++r) {
    __syncthreads();  // zA/wT free for reuse
    // ---- aggregate this wave's 16 node rows (fp32), write bf16 to LDS
    for (int i = 0; i < 16; ++i) {
      const int row = wave * 16 + i;
      const int n = nodeBase + row;
      float a0 = 0.f, a1 = 0.f, nd = 0.f;
      if (n < N_NODES) {
        const int d = deg_in[r * N_NODES + n];
        const int off = csr_off[r * N_NODES + n];
        const int* __restrict__ lst = csr_src + (size_t)r * NEDGE + off;
        for (int e = 0; e < d; ++e) {
          const int s = lst[e];
          const float w = norm_src[r * N_NODES + s];
          const float2 v = *(const float2*)(x + (size_t)s * FDIM + lane * 2);
          a0 += v.x * w;
          a1 += v.y * w;
        }
        nd = norm_dst[r * N_NODES + n];
      }
      const unsigned int pk =
          (unsigned int)f2bf(a0 * nd) | ((unsigned int)f2bf(a1 * nd) << 16);
      *(unsigned int*)(&zA[row][lane * 2]) = pk;
    }
    // ---- stage W1T[r] -> wT (straight copy; already transposed+bf16)
    {
      const unsigned short* __restrict__ wsrc = W1T + r * (FDIM * HID);
#pragma unroll
      for (int i = 0; i < 8; ++i) {
        const int chunk = tid + i * 256;  // 0..2047 chunks of 8 ushorts
        const int j = chunk >> 4;
        const int c = chunk & 15;
        const uint4 v = *(const uint4*)(wsrc + chunk * 8);
        *(uint4*)(&wT[j][c * 8]) = v;
      }
    }
    __syncthreads();
    // ---- MFMA: D[node][feat] += zA(16x128) * W^T
    const int m = lane & 15;
    const int q = lane >> 4;
#pragma unroll
    for (int kk = 0; kk < 4; ++kk) {
      const short8 af = *(const short8*)(&zA[wave * 16 + m][kk * 32 + q * 8]);
#pragma unroll
      for (int t = 0; t < 8; ++t) {
        const short8 bfr = *(const short8*)(&wT[t * 16 + m][kk * 32 + q * 8]);
        acc[t] = __builtin_amdgcn_mfma_f32_16x16x32_bf16(af, bfr, acc[t], 0, 0, 0);
      }
    }
  }
  // ---- epilogue: bias + relu, store bf16
  const int col = lane & 15;
  const int rq = (lane >> 4) * 4;
#pragma unroll
  for (int t = 0; t < 8; ++t) {
#pragma unroll
    for (int rr = 0; rr < 4; ++rr) {
      const int node = nodeBase + wave * 16 + rq + rr;
      if (node < N_NODES) {
        const int f = t * 16 + col;
        float v = acc[t][rr] + bias1[f];
        v = fmaxf(v, 0.f);
        h[(size_t)node * FDIM + f] = f2bf(v);
      }
    }
  }
}

// ---------------- layer-2 folded: mv[r] = (1/N) sum_n coef'_r[n] * h[n] ----------------
__global__ __launch_bounds__(256) void k_mv(const unsigned short* __restrict__ h,
                                            const float* __restrict__ coef,
                                            const float* __restrict__ norm_src,
                                            float* __restrict__ mv) {
  const int wave = threadIdx.x >> 6;
  const int lane = threadIdx.x & 63;
  const int base = blockIdx.x * 1024 + wave * 256;
  float acc[NREL][2];
#pragma unroll
  for (int r = 0; r < NREL; ++r) { acc[r][0] = 0.f; acc[r][1] = 0.f; }
  for (int i = 0; i < 256; ++i) {
    const int n = base + i;
    if (n >= N_NODES) break;
    const unsigned int hv = *(const unsigned int*)(h + (size_t)n * FDIM + lane * 2);
    const float h0 = bf2f(hv & 0xffffu);
    const float h1 = bf2f(hv >> 16);
#pragma unroll
    for (int r = 0; r < NREL; ++r) {
      const float c = coef[r * N_NODES + n] * norm_src[r * N_NODES + n];
      acc[r][0] += c * h0;
      acc[r][1] += c * h1;
    }
  }
  const float inv = 1.0f / (float)N_NODES;
#pragma unroll
  for (int r = 0; r < NREL; ++r) {
    atomicAdd(&mv[r * HID + lane * 2], acc[r][0] * inv);
    atomicAdd(&mv[r * HID + lane * 2 + 1], acc[r][1] * inv);
  }
}

// ---------------- final: out = (sum_r mv_r @ W2[r] + sum_r b2[r]) @ Wc + bc ----------------
__global__ void k_final(const float* __restrict__ mv, const float* __restrict__ W2,
                        const float* __restrict__ bias2, const float* __restrict__ Wc,
                        const float* __restrict__ bc, float* __restrict__ out) {
  __shared__ float g[HID];
  const int j = threadIdx.x;
  float acc = bias2[j];
  for (int r = 0; r < NREL; ++r) {
#pragma unroll 4
    for (int k = 0; k < HID; ++k) {
      acc += mv[r * HID + k] * W2[r * HID * HID + k * HID + j];
    }
  }
  g[j] = acc;
  __syncthreads();
  if (j < 2) {
    float o = bc[j];
    for (int k = 0; k < HID; ++k) o += g[k] * Wc[k * 2 + j];
    out[j] = o;
  }
}

extern "C" void kernel_launch(void* const* d_in, const int* in_sizes, int n_in,
                              void* d_out, int out_size, void* d_ws, size_t ws_size,
                              hipStream_t stream) {
  (void)in_sizes; (void)n_in; (void)out_size; (void)ws_size;
  const float* x   = (const float*)d_in[0];
  const int* esrc  = (const int*)d_in[1];
  const int* edst  = (const int*)d_in[2];
  const float* W1  = (const float*)d_in[3];
  const float* b1  = (const float*)d_in[4];
  const float* W2  = (const float*)d_in[5];
  const float* b2  = (const float*)d_in[6];
  const float* Wc  = (const float*)d_in[7];
  const float* bc  = (const float*)d_in[8];
  float* out = (float*)d_out;

  char* p = (char*)d_ws;
  size_t off = 0;
  auto take = [&](size_t bytes) -> void* {
    void* q = p + off;
    off += (bytes + 255) & ~(size_t)255;
    return q;
  };
  // ---- zeroed region (contiguous, zeroed every call) ----
  int*   deg_in  = (int*)  take((size_t)RN * 4);
  int*   deg_out = (int*)  take((size_t)RN * 4);
  int*   cursor  = (int*)  take((size_t)RN * 4);
  float* coef    = (float*)take((size_t)RN * 4);
  float* mv      = (float*)take((size_t)NREL * HID * 4);
  const size_t zero_bytes = off;
  // ---- non-zeroed region ----
  float* norm_src = (float*)take((size_t)RN * 4);
  float* norm_dst = (float*)take((size_t)RN * 4);
  int*   csr_off  = (int*)  take((size_t)RN * 4);
  int*   csr_src  = (int*)  take((size_t)RE * 4);
  int*   blockSums= (int*)  take((size_t)NREL * NB_SCAN * 4 + 256);
  unsigned short* W1T = (unsigned short*)take((size_t)NREL * FDIM * HID * 2);
  float* bias1    = (float*)take(HID * 4);
  float* bias2    = (float*)take(HID * 4);
  unsigned short* h = (unsigned short*)take((size_t)N_NODES * FDIM * 2);

  const int zero_words = (int)(zero_bytes / 4);
  k_zero<<<(zero_words + 1023) / 1024, 1024, 0, stream>>>((unsigned int*)d_ws, zero_words);
  k_deg<<<(RE + 255) / 256, 256, 0, stream>>>(esrc, edst, deg_out, deg_in);
  k_norm<<<(RN + 255) / 256, 256, 0, stream>>>(deg_out, deg_in, norm_src, norm_dst);
  k_wconv<<<(NREL * FDIM * HID + 255) / 256, 256, 0, stream>>>(W1, b1, b2, W1T, bias1, bias2);
  k_coef<<<(RE + 255) / 256, 256, 0, stream>>>(esrc, edst, norm_dst, coef);
  k_scan1<<<NREL * NB_SCAN, 1024, 0, stream>>>(deg_in, csr_off, blockSums);
  k_scan2<<<1, 64, 0, stream>>>(blockSums);
  k_scan3<<<(RN + 255) / 256, 256, 0, stream>>>(csr_off, blockSums);
  k_fill<<<(RE + 255) / 256, 256, 0, stream>>>(esrc, edst, csr_off, cursor, csr_src);
  k_layer1<<<(N_NODES + 63) / 64, 256, 0, stream>>>(x, csr_src, csr_off, deg_in,
                                                    norm_src, norm_dst, W1T, bias1, h);
  k_mv<<<(N_NODES + 1023) / 1024, 256, 0, stream>>>(h, coef, norm_src, mv);
  k_final<<<1, HID, 0, stream>>>(mv, W2, bias2, Wc, bc, out);
}

// Round 2
// 981.648 us; speedup vs baseline: 1.6227x; 1.6227x over previous
//
#include <hip/hip_runtime.h>

#define N_NODES 100000
#define NREL 6
#define NEDGE 400000
#define FDIM 128
#define HID 128

constexpr int RN = NREL * N_NODES;   // 600000
constexpr int RE = NREL * NEDGE;     // 2400000
constexpr int NB_SCAN = (N_NODES + 1023) / 1024;  // 98

typedef __attribute__((ext_vector_type(8))) short short8;
typedef __attribute__((ext_vector_type(4))) float f32x4;

__device__ __forceinline__ unsigned short f2bf(float f) {
  union { float f; unsigned int u; } v; v.f = f;
  unsigned int u = v.u;
  unsigned int r = (u + 0x7FFFu + ((u >> 16) & 1u)) >> 16;
  return (unsigned short)r;
}
__device__ __forceinline__ float bf2f(unsigned int bits) {
  union { unsigned int u; float f; } v; v.u = bits << 16;
  return v.f;
}

// ---------------- zero workspace ----------------
__global__ void k_zero(unsigned int* __restrict__ p, int nwords) {
  int id = blockIdx.x * blockDim.x + threadIdx.x;
  if (id < nwords) p[id] = 0u;
}

// ---------------- degree histograms ----------------
__global__ void k_deg(const int* __restrict__ src, const int* __restrict__ dst,
                      int* __restrict__ deg_out, int* __restrict__ deg_in) {
  int id = blockIdx.x * 256 + threadIdx.x;
  if (id < RE) {
    int r = id / NEDGE;
    atomicAdd(&deg_out[r * N_NODES + src[id]], 1);
    atomicAdd(&deg_in[r * N_NODES + dst[id]], 1);
  }
}

// ---------------- norms ----------------
__global__ void k_norm(const int* __restrict__ deg_out, const int* __restrict__ deg_in,
                       float* __restrict__ norm_src, float* __restrict__ norm_dst) {
  int id = blockIdx.x * 256 + threadIdx.x;
  if (id < RN) {
    int dO = deg_out[id];
    int dI = deg_in[id];
    norm_src[id] = dO > 0 ? rsqrtf((float)dO) : 0.f;
    norm_dst[id] = dI > 0 ? rsqrtf((float)dI) : 0.f;
  }
}

// ---------------- x fp32 -> bf16 ----------------
__global__ void k_xconv(const float* __restrict__ x, unsigned short* __restrict__ xb) {
  int id = blockIdx.x * 256 + threadIdx.x;
  if (id < N_NODES * 32) {
    const float4 v = ((const float4*)x)[id];
    ushort4 o;
    o.x = f2bf(v.x); o.y = f2bf(v.y); o.z = f2bf(v.z); o.w = f2bf(v.w);
    ((ushort4*)xb)[id] = o;
  }
}

// ---------------- W1 transpose+bf16 convert, bias sums ----------------
__global__ void k_wconv(const float* __restrict__ W1, const float* __restrict__ b1,
                        const float* __restrict__ b2,
                        unsigned short* __restrict__ W1T,
                        float* __restrict__ bias1, float* __restrict__ bias2) {
  int id = blockIdx.x * 256 + threadIdx.x;
  if (id < NREL * FDIM * HID) {
    int r = id >> 14;
    int rem = id & 16383;
    int j = rem >> 7;      // output feature
    int k = rem & 127;     // input feature
    W1T[id] = f2bf(W1[r * 16384 + k * 128 + j]);  // W1T[r][j][k] = W1[r][k][j]
  }
  if (id < HID) {
    float s1 = 0.f, s2 = 0.f;
    for (int r = 0; r < NREL; ++r) {
      s1 += b1[r * HID + id];
      s2 += b2[r * HID + id];
    }
    bias1[id] = s1;
    bias2[id] = s2;
  }
}

// ---------------- scan (3 stages) for CSR offsets ----------------
__global__ __launch_bounds__(1024) void k_scan1(const int* __restrict__ deg_in,
                                                int* __restrict__ csr_off,
                                                int* __restrict__ blockSums) {
  __shared__ int sh[1024];
  int r = blockIdx.x / NB_SCAN;
  int b = blockIdx.x % NB_SCAN;
  int t = threadIdx.x;
  int n = b * 1024 + t;
  int v = (n < N_NODES) ? deg_in[r * N_NODES + n] : 0;
  sh[t] = v;
  __syncthreads();
  int sum = v;
  for (int offi = 1; offi < 1024; offi <<= 1) {
    int y = (t >= offi) ? sh[t - offi] : 0;
    __syncthreads();
    sum += y;
    sh[t] = sum;
    __syncthreads();
  }
  if (n < N_NODES) csr_off[r * N_NODES + n] = sum - v;  // exclusive
  if (t == 1023) blockSums[blockIdx.x] = sum;
}

__global__ void k_scan2(int* __restrict__ blockSums) {
  int r = threadIdx.x;
  if (r < NREL) {
    int run = 0;
    for (int b = 0; b < NB_SCAN; ++b) {
      int t = blockSums[r * NB_SCAN + b];
      blockSums[r * NB_SCAN + b] = run;
      run += t;
    }
  }
}

__global__ void k_scan3(int* __restrict__ csr_off, const int* __restrict__ blockSums) {
  int id = blockIdx.x * 256 + threadIdx.x;
  if (id < RN) {
    int r = id / N_NODES;
    int n = id - r * N_NODES;
    csr_off[id] += blockSums[r * NB_SCAN + (n >> 10)];
  }
}

// ---------------- CSR fill (+ coef accumulation fused) ----------------
__global__ void k_fill(const int* __restrict__ src, const int* __restrict__ dst,
                       const int* __restrict__ csr_off, int* __restrict__ cursor,
                       const float* __restrict__ norm_src, const float* __restrict__ norm_dst,
                       int2* __restrict__ csr_ew, float* __restrict__ coef) {
  int id = blockIdx.x * 256 + threadIdx.x;
  if (id < RE) {
    int r = id / NEDGE;
    int rN = r * N_NODES;
    int s = src[id];
    int dd = dst[id];
    int p = atomicAdd(&cursor[rN + dd], 1);
    atomicAdd(&coef[rN + s], norm_dst[rN + dd]);
    int2 ew;
    ew.x = s;
    ew.y = __float_as_int(norm_src[rN + s]);
    csr_ew[(size_t)r * NEDGE + csr_off[rN + dd] + p] = ew;
  }
}

// ---------------- fused layer-1: aggregate (2 rows/wave, 4-edge batches) + MFMA ----------------
__global__ __launch_bounds__(256, 4) void k_layer1(
    const unsigned short* __restrict__ xb,   // [N][128] bf16
    const int2* __restrict__ csr_ew,         // [R][E] {src, norm_src bits}
    const int* __restrict__ csr_off,
    const int* __restrict__ deg_in,
    const float* __restrict__ norm_dst,
    const unsigned short* __restrict__ W1T,  // [R][128][128] bf16 (out_feat, in_feat)
    const float* __restrict__ bias1,
    unsigned short* __restrict__ h)          // [N][128] bf16
{
  __shared__ unsigned short zA[64][136];     // stride 272B: 16B-aligned rows
  __shared__ unsigned short wT[128][136];
  const int tid = threadIdx.x;
  const int wave = tid >> 6;
  const int lane = tid & 63;
  const int half = lane >> 5;       // which of 2 concurrent rows
  const int flane = lane & 31;      // 4 bf16 features per lane
  const int nodeBase = blockIdx.x * 64;

  f32x4 acc[8];
#pragma unroll
  for (int t = 0; t < 8; ++t) acc[t] = (f32x4){0.f, 0.f, 0.f, 0.f};

  for (int r = 0; r < NREL; ++r) {
    const int rN = r * N_NODES;
    // preload this wave's 16 rows' meta into lanes 0..15
    int dP = 0, oP = 0;
    float ndP = 0.f;
    {
      const int pn = nodeBase + wave * 16 + (lane & 15);
      if (lane < 16 && pn < N_NODES) {
        dP = deg_in[rN + pn];
        oP = csr_off[rN + pn];
        ndP = norm_dst[rN + pn];
      }
    }
    __syncthreads();  // zA/wT free for reuse
    const int2* __restrict__ rel = csr_ew + (size_t)r * NEDGE;
    for (int i = 0; i < 8; ++i) {
      const int rsel = i * 2 + half;
      const int d = __shfl(dP, rsel);
      const int o = __shfl(oP, rsel);
      const float nd = __shfl(ndP, rsel);
      float a0 = 0.f, a1 = 0.f, a2 = 0.f, a3 = 0.f;
      const int2* __restrict__ lst = rel + o;
      const unsigned int fo = (unsigned int)(flane << 2);
      int e = 0;
      for (; e + 4 <= d; e += 4) {
        const int2 p0 = lst[e], p1 = lst[e + 1], p2 = lst[e + 2], p3 = lst[e + 3];
        const uint2 v0 = *(const uint2*)(xb + (((unsigned)p0.x) << 7) + fo);
        const uint2 v1 = *(const uint2*)(xb + (((unsigned)p1.x) << 7) + fo);
        const uint2 v2 = *(const uint2*)(xb + (((unsigned)p2.x) << 7) + fo);
        const uint2 v3 = *(const uint2*)(xb + (((unsigned)p3.x) << 7) + fo);
        const float w0 = __int_as_float(p0.y), w1 = __int_as_float(p1.y);
        const float w2 = __int_as_float(p2.y), w3 = __int_as_float(p3.y);
        a0 = fmaf(bf2f(v0.x & 0xffffu), w0, a0);
        a1 = fmaf(bf2f(v0.x >> 16),     w0, a1);
        a2 = fmaf(bf2f(v0.y & 0xffffu), w0, a2);
        a3 = fmaf(bf2f(v0.y >> 16),     w0, a3);
        a0 = fmaf(bf2f(v1.x & 0xffffu), w1, a0);
        a1 = fmaf(bf2f(v1.x >> 16),     w1, a1);
        a2 = fmaf(bf2f(v1.y & 0xffffu), w1, a2);
        a3 = fmaf(bf2f(v1.y >> 16),     w1, a3);
        a0 = fmaf(bf2f(v2.x & 0xffffu), w2, a0);
        a1 = fmaf(bf2f(v2.x >> 16),     w2, a1);
        a2 = fmaf(bf2f(v2.y & 0xffffu), w2, a2);
        a3 = fmaf(bf2f(v2.y >> 16),     w2, a3);
        a0 = fmaf(bf2f(v3.x & 0xffffu), w3, a0);
        a1 = fmaf(bf2f(v3.x >> 16),     w3, a1);
        a2 = fmaf(bf2f(v3.y & 0xffffu), w3, a2);
        a3 = fmaf(bf2f(v3.y >> 16),     w3, a3);
      }
      for (; e < d; ++e) {
        const int2 p0 = lst[e];
        const uint2 v0 = *(const uint2*)(xb + (((unsigned)p0.x) << 7) + fo);
        const float w0 = __int_as_float(p0.y);
        a0 = fmaf(bf2f(v0.x & 0xffffu), w0, a0);
        a1 = fmaf(bf2f(v0.x >> 16),     w0, a1);
        a2 = fmaf(bf2f(v0.y & 0xffffu), w0, a2);
        a3 = fmaf(bf2f(v0.y >> 16),     w0, a3);
      }
      uint2 pk;
      pk.x = (unsigned int)f2bf(a0 * nd) | ((unsigned int)f2bf(a1 * nd) << 16);
      pk.y = (unsigned int)f2bf(a2 * nd) | ((unsigned int)f2bf(a3 * nd) << 16);
      *(uint2*)(&zA[wave * 16 + i * 2 + half][flane * 4]) = pk;
    }
    // ---- stage W1T[r] -> wT
    {
      const unsigned short* __restrict__ wsrc = W1T + r * (FDIM * HID);
#pragma unroll
      for (int it = 0; it < 8; ++it) {
        const int chunk = tid + it * 256;
        const int j = chunk >> 4;
        const int c = chunk & 15;
        *(uint4*)(&wT[j][c * 8]) = *(const uint4*)(wsrc + chunk * 8);
      }
    }
    __syncthreads();
    // ---- MFMA: D[node][feat] += zA(16x128) * W^T
    const int m = lane & 15;
    const int q = lane >> 4;
#pragma unroll
    for (int kk = 0; kk < 4; ++kk) {
      const short8 af = *(const short8*)(&zA[wave * 16 + m][kk * 32 + q * 8]);
#pragma unroll
      for (int t = 0; t < 8; ++t) {
        const short8 bfr = *(const short8*)(&wT[t * 16 + m][kk * 32 + q * 8]);
        acc[t] = __builtin_amdgcn_mfma_f32_16x16x32_bf16(af, bfr, acc[t], 0, 0, 0);
      }
    }
  }
  // ---- epilogue: bias + relu, store bf16
  const int col = lane & 15;
  const int rq = (lane >> 4) * 4;
#pragma unroll
  for (int t = 0; t < 8; ++t) {
#pragma unroll
    for (int rr = 0; rr < 4; ++rr) {
      const int node = nodeBase + wave * 16 + rq + rr;
      if (node < N_NODES) {
        const int f = t * 16 + col;
        float v = acc[t][rr] + bias1[f];
        v = fmaxf(v, 0.f);
        h[(size_t)node * FDIM + f] = f2bf(v);
      }
    }
  }
}

// ---------------- layer-2 folded: mv[r] = (1/N) sum_n cc_r[n] * h[n] ----------------
__global__ __launch_bounds__(256) void k_mv(const unsigned short* __restrict__ h,
                                            const float* __restrict__ coef,
                                            const float* __restrict__ norm_src,
                                            float* __restrict__ mv) {
  const int wave = threadIdx.x >> 6;
  const int lane = threadIdx.x & 63;
  const int base = blockIdx.x * 256 + wave * 64;
  float ccP[NREL];
  const int pn = base + lane;
#pragma unroll
  for (int r = 0; r < NREL; ++r) {
    ccP[r] = (pn < N_NODES) ? coef[r * N_NODES + pn] * norm_src[r * N_NODES + pn] : 0.f;
  }
  float accv[NREL][2];
#pragma unroll
  for (int r = 0; r < NREL; ++r) { accv[r][0] = 0.f; accv[r][1] = 0.f; }
  if (base < N_NODES) {
    const int lim = min(64, N_NODES - base);
    for (int i = 0; i < lim; ++i) {
      const unsigned int hv = *(const unsigned int*)(h + (size_t)(base + i) * FDIM + lane * 2);
      const float h0 = bf2f(hv & 0xffffu);
      const float h1 = bf2f(hv >> 16);
#pragma unroll
      for (int r = 0; r < NREL; ++r) {
        const float c = __shfl(ccP[r], i);
        accv[r][0] = fmaf(c, h0, accv[r][0]);
        accv[r][1] = fmaf(c, h1, accv[r][1]);
      }
    }
  }
  const float inv = 1.0f / (float)N_NODES;
#pragma unroll
  for (int r = 0; r < NREL; ++r) {
    atomicAdd(&mv[r * HID + lane * 2], accv[r][0] * inv);
    atomicAdd(&mv[r * HID + lane * 2 + 1], accv[r][1] * inv);
  }
}

// ---------------- final: out = (sum_r mv_r @ W2[r] + bias2) @ Wc + bc ----------------
__global__ __launch_bounds__(768) void k_final(const float* __restrict__ mv,
                                               const float* __restrict__ W2,
                                               const float* __restrict__ bias2,
                                               const float* __restrict__ Wc,
                                               const float* __restrict__ bc,
                                               float* __restrict__ out) {
  __shared__ float g[NREL][HID];
  __shared__ float gs[HID];
  const int tid = threadIdx.x;
  const int r = tid >> 7;
  const int j = tid & 127;
  float acc = 0.f;
#pragma unroll 4
  for (int k = 0; k < HID; ++k) {
    acc += mv[r * HID + k] * W2[r * HID * HID + k * HID + j];
  }
  g[r][j] = acc;
  __syncthreads();
  if (tid < HID) {
    float s = bias2[tid];
#pragma unroll
    for (int rr = 0; rr < NREL; ++rr) s += g[rr][tid];
    gs[tid] = s;
  }
  __syncthreads();
  if (tid < 2) {
    float o = bc[tid];
    for (int k = 0; k < HID; ++k) o += gs[k] * Wc[k * 2 + tid];
    out[tid] = o;
  }
}

extern "C" void kernel_launch(void* const* d_in, const int* in_sizes, int n_in,
                              void* d_out, int out_size, void* d_ws, size_t ws_size,
                              hipStream_t stream) {
  (void)in_sizes; (void)n_in; (void)out_size; (void)ws_size;
  const float* x   = (const float*)d_in[0];
  const int* esrc  = (const int*)d_in[1];
  const int* edst  = (const int*)d_in[2];
  const float* W1  = (const float*)d_in[3];
  const float* b1  = (const float*)d_in[4];
  const float* W2  = (const float*)d_in[5];
  const float* b2  = (const float*)d_in[6];
  const float* Wc  = (const float*)d_in[7];
  const float* bc  = (const float*)d_in[8];
  float* out = (float*)d_out;

  char* p = (char*)d_ws;
  size_t off = 0;
  auto take = [&](size_t bytes) -> void* {
    void* q = p + off;
    off += (bytes + 255) & ~(size_t)255;
    return q;
  };
  // ---- zeroed region (contiguous, zeroed every call) ----
  int*   deg_in  = (int*)  take((size_t)RN * 4);
  int*   deg_out = (int*)  take((size_t)RN * 4);
  int*   cursor  = (int*)  take((size_t)RN * 4);
  float* coef    = (float*)take((size_t)RN * 4);
  float* mv      = (float*)take((size_t)NREL * HID * 4);
  const size_t zero_bytes = off;
  // ---- non-zeroed region ----
  float* norm_src = (float*)take((size_t)RN * 4);
  float* norm_dst = (float*)take((size_t)RN * 4);
  int*   csr_off  = (int*)  take((size_t)RN * 4);
  int2*  csr_ew   = (int2*) take((size_t)RE * 8);
  int*   blockSums= (int*)  take((size_t)NREL * NB_SCAN * 4 + 256);
  unsigned short* W1T = (unsigned short*)take((size_t)NREL * FDIM * HID * 2);
  float* bias1    = (float*)take(HID * 4);
  float* bias2    = (float*)take(HID * 4);
  unsigned short* h  = (unsigned short*)take((size_t)N_NODES * FDIM * 2);
  unsigned short* xb = (unsigned short*)take((size_t)N_NODES * FDIM * 2);

  const int zero_words = (int)(zero_bytes / 4);
  k_zero<<<(zero_words + 1023) / 1024, 1024, 0, stream>>>((unsigned int*)d_ws, zero_words);
  k_deg<<<(RE + 255) / 256, 256, 0, stream>>>(esrc, edst, deg_out, deg_in);
  k_norm<<<(RN + 255) / 256, 256, 0, stream>>>(deg_out, deg_in, norm_src, norm_dst);
  k_xconv<<<(N_NODES * 32 + 255) / 256, 256, 0, stream>>>(x, xb);
  k_wconv<<<(NREL * FDIM * HID + 255) / 256, 256, 0, stream>>>(W1, b1, b2, W1T, bias1, bias2);
  k_scan1<<<NREL * NB_SCAN, 1024, 0, stream>>>(deg_in, csr_off, blockSums);
  k_scan2<<<1, 64, 0, stream>>>(blockSums);
  k_scan3<<<(RN + 255) / 256, 256, 0, stream>>>(csr_off, blockSums);
  k_fill<<<(RE + 255) / 256, 256, 0, stream>>>(esrc, edst, csr_off, cursor,
                                               norm_src, norm_dst, csr_ew, coef);
  k_layer1<<<(N_NODES + 63) / 64, 256, 0, stream>>>(xb, csr_ew, csr_off, deg_in,
                                                    norm_dst, W1T, bias1, h);
  k_mv<<<(N_NODES + 255) / 256, 256, 0, stream>>>(h, coef, norm_src, mv);
  k_final<<<1, 768, 0, stream>>>(mv, W2, bias2, Wc, bc, out);
}

// Round 3
// 893.773 us; speedup vs baseline: 1.7822x; 1.0983x over previous
//
#include <hip/hip_runtime.h>

#define N_NODES 100000
#define NREL 6
#define NEDGE 400000
#define FDIM 128
#define HID 128
#define PADCAP (NEDGE + 3 * N_NODES)   // 700000: padded-CSR capacity per relation

constexpr int RN = NREL * N_NODES;   // 600000
constexpr int RE = NREL * NEDGE;     // 2400000
constexpr int NB_SCAN = (N_NODES + 1023) / 1024;  // 98

typedef __attribute__((ext_vector_type(8))) short short8;
typedef __attribute__((ext_vector_type(4))) float f32x4;

__device__ __forceinline__ unsigned short f2bf(float f) {
  union { float f; unsigned int u; } v; v.f = f;
  unsigned int u = v.u;
  unsigned int r = (u + 0x7FFFu + ((u >> 16) & 1u)) >> 16;
  return (unsigned short)r;
}
__device__ __forceinline__ float bflo(unsigned int w) {
  union { unsigned int u; float f; } v; v.u = w << 16; return v.f;
}
__device__ __forceinline__ float bfhi(unsigned int w) {
  union { unsigned int u; float f; } v; v.u = w & 0xffff0000u; return v.f;
}

// ---------------- zero workspace (uint4 stores) ----------------
__global__ void k_zero(uint4* __restrict__ p, int nq) {
  int id = blockIdx.x * blockDim.x + threadIdx.x;
  if (id < nq) p[id] = (uint4){0u, 0u, 0u, 0u};
}

// ---------------- degree histograms ----------------
__global__ void k_deg(const int* __restrict__ src, const int* __restrict__ dst,
                      int* __restrict__ deg_out, int* __restrict__ deg_in) {
  int id = blockIdx.x * 256 + threadIdx.x;
  if (id < RE) {
    int r = id / NEDGE;
    atomicAdd(&deg_out[r * N_NODES + src[id]], 1);
    atomicAdd(&deg_in[r * N_NODES + dst[id]], 1);
  }
}

// ---------------- norms ----------------
__global__ void k_norm(const int* __restrict__ deg_out, const int* __restrict__ deg_in,
                       float* __restrict__ norm_src, float* __restrict__ norm_dst) {
  int id = blockIdx.x * 256 + threadIdx.x;
  if (id < RN) {
    int dO = deg_out[id];
    int dI = deg_in[id];
    norm_src[id] = dO > 0 ? rsqrtf((float)dO) : 0.f;
    norm_dst[id] = dI > 0 ? rsqrtf((float)dI) : 0.f;
  }
}

// ---------------- x fp32 -> bf16 ----------------
__global__ void k_xconv(const float* __restrict__ x, unsigned short* __restrict__ xb) {
  int id = blockIdx.x * 256 + threadIdx.x;
  if (id < N_NODES * 32) {
    const float4 v = ((const float4*)x)[id];
    ushort4 o;
    o.x = f2bf(v.x); o.y = f2bf(v.y); o.z = f2bf(v.z); o.w = f2bf(v.w);
    ((ushort4*)xb)[id] = o;
  }
}

// ---------------- W1 transpose+bf16 convert, bias sums ----------------
__global__ void k_wconv(const float* __restrict__ W1, const float* __restrict__ b1,
                        const float* __restrict__ b2,
                        unsigned short* __restrict__ W1T,
                        float* __restrict__ bias1, float* __restrict__ bias2) {
  int id = blockIdx.x * 256 + threadIdx.x;
  if (id < NREL * FDIM * HID) {
    int r = id >> 14;
    int rem = id & 16383;
    int j = rem >> 7;      // output feature
    int k = rem & 127;     // input feature
    W1T[id] = f2bf(W1[r * 16384 + k * 128 + j]);  // W1T[r][j][k] = W1[r][k][j]
  }
  if (id < HID) {
    float s1 = 0.f, s2 = 0.f;
    for (int r = 0; r < NREL; ++r) {
      s1 += b1[r * HID + id];
      s2 += b2[r * HID + id];
    }
    bias1[id] = s1;
    bias2[id] = s2;
  }
}

// ---------------- u[r][k][c] = sum_j W2[r][k][j] * Wc[j][c] ----------------
__global__ void k_u(const float* __restrict__ W2, const float* __restrict__ Wc,
                    float* __restrict__ u) {
  const int r = blockIdx.x;
  const int k = threadIdx.x >> 1;
  const int c = threadIdx.x & 1;
  const float* __restrict__ row = W2 + r * (HID * HID) + k * HID;
  float s = 0.f;
#pragma unroll 8
  for (int j = 0; j < HID; ++j) s = fmaf(row[j], Wc[j * 2 + c], s);
  u[(r * HID + k) * 2 + c] = s;
}

// ---------------- scan stage 1: padded degrees, per-1024 block ----------------
__global__ __launch_bounds__(1024) void k_scan1(const int* __restrict__ deg_in,
                                                int* __restrict__ csr_off,
                                                int* __restrict__ blockSums) {
  __shared__ int ws[16];
  const int r = blockIdx.x / NB_SCAN;
  const int b = blockIdx.x % NB_SCAN;
  const int t = threadIdx.x;
  const int wid = t >> 6;
  const int lane = t & 63;
  const int n = b * 1024 + t;
  const int v = (n < N_NODES) ? ((deg_in[r * N_NODES + n] + 3) & ~3) : 0;
  int sum = v;
#pragma unroll
  for (int off = 1; off < 64; off <<= 1) {
    int y = __shfl_up(sum, off);
    if (lane >= off) sum += y;
  }
  if (lane == 63) ws[wid] = sum;
  __syncthreads();
  if (wid == 0) {
    int s2 = (lane < 16) ? ws[lane] : 0;
#pragma unroll
    for (int off = 1; off < 16; off <<= 1) {
      int y = __shfl_up(s2, off);
      if (lane >= off) s2 += y;
    }
    if (lane < 16) ws[lane] = s2;
  }
  __syncthreads();
  if (wid > 0) sum += ws[wid - 1];
  if (n < N_NODES) csr_off[r * N_NODES + n] = sum - v;  // exclusive
  if (t == 1023) blockSums[blockIdx.x] = sum;
}

// ---------------- scan stage 2: exclusive scan of 98 block sums per relation ----------------
__global__ __launch_bounds__(768) void k_scan2(int* __restrict__ blockSums) {
  __shared__ int sh[NREL][128];
  const int t = threadIdx.x;
  const int r = t >> 7;
  const int b = t & 127;
  const int v = (b < NB_SCAN) ? blockSums[r * NB_SCAN + b] : 0;
  int cur = v;
  sh[r][b] = cur;
  __syncthreads();
  for (int off = 1; off < 128; off <<= 1) {
    int y = (b >= off) ? sh[r][b - off] : 0;
    __syncthreads();
    cur += y;
    sh[r][b] = cur;
    __syncthreads();
  }
  if (b < NB_SCAN) blockSums[r * NB_SCAN + b] = cur - v;  // exclusive
}

__global__ void k_scan3(int* __restrict__ csr_off, const int* __restrict__ blockSums) {
  int id = blockIdx.x * 256 + threadIdx.x;
  if (id < RN) {
    int r = id / N_NODES;
    int n = id - r * N_NODES;
    csr_off[id] += blockSums[r * NB_SCAN + (n >> 10)];
  }
}

// ---------------- CSR fill (+ coef accumulation fused) ----------------
__global__ void k_fill(const int* __restrict__ src, const int* __restrict__ dst,
                       const int* __restrict__ csr_off, int* __restrict__ cursor,
                       const float* __restrict__ norm_src, const float* __restrict__ norm_dst,
                       int2* __restrict__ csr_ew, float* __restrict__ coef) {
  int id = blockIdx.x * 256 + threadIdx.x;
  if (id < RE) {
    int r = id / NEDGE;
    int rN = r * N_NODES;
    int s = src[id];
    int dd = dst[id];
    int p = atomicAdd(&cursor[rN + dd], 1);
    atomicAdd(&coef[rN + s], norm_dst[rN + dd]);
    int2 ew;
    ew.x = s;
    ew.y = __float_as_int(norm_src[rN + s]);
    csr_ew[(size_t)r * PADCAP + csr_off[rN + dd] + p] = ew;
  }
}

// ---------------- fused layer-1: 4 rows/wave, 16 gathers in flight, MFMA ----------------
__global__ __launch_bounds__(256, 4) void k_layer1(
    const unsigned short* __restrict__ xb,   // [N][128] bf16
    const int2* __restrict__ csr_ew,         // [R][PADCAP] {src, norm_src bits}
    const int* __restrict__ csr_off,         // padded exclusive offsets
    const int* __restrict__ deg_in,
    const float* __restrict__ norm_dst,
    const unsigned short* __restrict__ W1T,  // [R][128][128] bf16 (out_feat, in_feat)
    const float* __restrict__ bias1,
    unsigned short* __restrict__ h)          // [N][128] bf16
{
  __shared__ unsigned short zA[64][136];     // only A-tile in LDS (17.4 KB)
  const int tid = threadIdx.x;
  const int wave = tid >> 6;
  const int lane = tid & 63;
  const int sub = lane >> 4;        // which of 4 concurrent rows
  const int flane = lane & 15;      // 8 bf16 features per lane
  const int nodeBase = blockIdx.x * 64;

  f32x4 acc[8];
#pragma unroll
  for (int t = 0; t < 8; ++t) acc[t] = (f32x4){0.f, 0.f, 0.f, 0.f};

  for (int r = 0; r < NREL; ++r) {
    const int rN = r * N_NODES;
    // meta for this wave's 16 rows in lanes 0..15
    int dP = 0, oP = 0;
    float ndP = 0.f;
    {
      const int pn = nodeBase + wave * 16 + flane;
      if (lane < 16 && pn < N_NODES) {
        dP = deg_in[rN + pn];
        oP = csr_off[rN + pn];
        ndP = norm_dst[rN + pn];
      }
    }
    __syncthreads();  // zA free for reuse
    const int2* __restrict__ rel = csr_ew + (size_t)r * PADCAP;
    for (int i = 0; i < 4; ++i) {
      const int rsel = i * 4 + sub;
      const int d = __shfl(dP, rsel);
      const int o = __shfl(oP, rsel);
      const float nd = __shfl(ndP, rsel);
      float a0 = 0.f, a1 = 0.f, a2 = 0.f, a3 = 0.f;
      float a4 = 0.f, a5 = 0.f, a6 = 0.f, a7 = 0.f;
      const int2* __restrict__ lst = rel + o;
      const int nb = (d + 3) >> 2;
      for (int bi = 0; bi < nb; ++bi) {
        const int e = bi * 4;
        const int2 p0 = lst[e], p1 = lst[e + 1], p2 = lst[e + 2], p3 = lst[e + 3];
        // predicate tail (w=0) + clamp garbage indices
        const float w0 = __int_as_float(p0.y);
        const float w1 = (e + 1 < d) ? __int_as_float(p1.y) : 0.f;
        const float w2 = (e + 2 < d) ? __int_as_float(p2.y) : 0.f;
        const float w3 = (e + 3 < d) ? __int_as_float(p3.y) : 0.f;
        const unsigned s0 = ((unsigned)p0.x < (unsigned)N_NODES) ? (unsigned)p0.x : 0u;
        const unsigned s1 = ((unsigned)p1.x < (unsigned)N_NODES) ? (unsigned)p1.x : 0u;
        const unsigned s2 = ((unsigned)p2.x < (unsigned)N_NODES) ? (unsigned)p2.x : 0u;
        const unsigned s3 = ((unsigned)p3.x < (unsigned)N_NODES) ? (unsigned)p3.x : 0u;
        const unsigned fo = (unsigned)(flane << 3);
        const uint4 v0 = *(const uint4*)(xb + (s0 << 7) + fo);
        const uint4 v1 = *(const uint4*)(xb + (s1 << 7) + fo);
        const uint4 v2 = *(const uint4*)(xb + (s2 << 7) + fo);
        const uint4 v3 = *(const uint4*)(xb + (s3 << 7) + fo);
        a0 = fmaf(bflo(v0.x), w0, a0); a1 = fmaf(bfhi(v0.x), w0, a1);
        a2 = fmaf(bflo(v0.y), w0, a2); a3 = fmaf(bfhi(v0.y), w0, a3);
        a4 = fmaf(bflo(v0.z), w0, a4); a5 = fmaf(bfhi(v0.z), w0, a5);
        a6 = fmaf(bflo(v0.w), w0, a6); a7 = fmaf(bfhi(v0.w), w0, a7);
        a0 = fmaf(bflo(v1.x), w1, a0); a1 = fmaf(bfhi(v1.x), w1, a1);
        a2 = fmaf(bflo(v1.y), w1, a2); a3 = fmaf(bfhi(v1.y), w1, a3);
        a4 = fmaf(bflo(v1.z), w1, a4); a5 = fmaf(bfhi(v1.z), w1, a5);
        a6 = fmaf(bflo(v1.w), w1, a6); a7 = fmaf(bfhi(v1.w), w1, a7);
        a0 = fmaf(bflo(v2.x), w2, a0); a1 = fmaf(bfhi(v2.x), w2, a1);
        a2 = fmaf(bflo(v2.y), w2, a2); a3 = fmaf(bfhi(v2.y), w2, a3);
        a4 = fmaf(bflo(v2.z), w2, a4); a5 = fmaf(bfhi(v2.z), w2, a5);
        a6 = fmaf(bflo(v2.w), w2, a6); a7 = fmaf(bfhi(v2.w), w2, a7);
        a0 = fmaf(bflo(v3.x), w3, a0); a1 = fmaf(bfhi(v3.x), w3, a1);
        a2 = fmaf(bflo(v3.y), w3, a2); a3 = fmaf(bfhi(v3.y), w3, a3);
        a4 = fmaf(bflo(v3.z), w3, a4); a5 = fmaf(bfhi(v3.z), w3, a5);
        a6 = fmaf(bflo(v3.w), w3, a6); a7 = fmaf(bfhi(v3.w), w3, a7);
      }
      uint4 pk;
      pk.x = (unsigned)f2bf(a0 * nd) | ((unsigned)f2bf(a1 * nd) << 16);
      pk.y = (unsigned)f2bf(a2 * nd) | ((unsigned)f2bf(a3 * nd) << 16);
      pk.z = (unsigned)f2bf(a4 * nd) | ((unsigned)f2bf(a5 * nd) << 16);
      pk.w = (unsigned)f2bf(a6 * nd) | ((unsigned)f2bf(a7 * nd) << 16);
      *(uint4*)(&zA[wave * 16 + i * 4 + sub][flane * 8]) = pk;
    }
    __syncthreads();
    // ---- MFMA: D[node][feat] += zA(16x128) * W^T, B-fragments direct from global (L1-hot)
    const int m = lane & 15;
    const int q = lane >> 4;
    const unsigned short* __restrict__ wr = W1T + r * (FDIM * HID);
#pragma unroll
    for (int kk = 0; kk < 4; ++kk) {
      const short8 af = *(const short8*)(&zA[wave * 16 + m][kk * 32 + q * 8]);
#pragma unroll
      for (int t = 0; t < 8; ++t) {
        const short8 bfr = *(const short8*)(wr + (t * 16 + m) * 128 + kk * 32 + q * 8);
        acc[t] = __builtin_amdgcn_mfma_f32_16x16x32_bf16(af, bfr, acc[t], 0, 0, 0);
      }
    }
  }
  // ---- epilogue: bias + relu, store bf16
  const int col = lane & 15;
  const int rq = (lane >> 4) * 4;
#pragma unroll
  for (int t = 0; t < 8; ++t) {
#pragma unroll
    for (int rr = 0; rr < 4; ++rr) {
      const int node = nodeBase + wave * 16 + rq + rr;
      if (node < N_NODES) {
        const int f = t * 16 + col;
        float v = acc[t][rr] + bias1[f];
        v = fmaxf(v, 0.f);
        h[(size_t)node * FDIM + f] = f2bf(v);
      }
    }
  }
}

// ---------------- layer-2 folded: mv[r] = (1/N) sum_n cc_r[n] * h[n] ----------------
__global__ __launch_bounds__(256) void k_mv(const unsigned short* __restrict__ h,
                                            const float* __restrict__ coef,
                                            const float* __restrict__ norm_src,
                                            float* __restrict__ mv) {
  const int wave = threadIdx.x >> 6;
  const int lane = threadIdx.x & 63;
  const int base = blockIdx.x * 256 + wave * 64;
  float ccP[NREL];
  const int pn = base + lane;
#pragma unroll
  for (int r = 0; r < NREL; ++r) {
    ccP[r] = (pn < N_NODES) ? coef[r * N_NODES + pn] * norm_src[r * N_NODES + pn] : 0.f;
  }
  float accv[NREL][2];
#pragma unroll
  for (int r = 0; r < NREL; ++r) { accv[r][0] = 0.f; accv[r][1] = 0.f; }
  if (base < N_NODES) {
    const int lim = min(64, N_NODES - base);
    for (int i = 0; i < lim; ++i) {
      const unsigned int hv = *(const unsigned int*)(h + (size_t)(base + i) * FDIM + lane * 2);
      const float h0 = bflo(hv);
      const float h1 = bfhi(hv);
#pragma unroll
      for (int r = 0; r < NREL; ++r) {
        const float c = __shfl(ccP[r], i);
        accv[r][0] = fmaf(c, h0, accv[r][0]);
        accv[r][1] = fmaf(c, h1, accv[r][1]);
      }
    }
  }
  const float inv = 1.0f / (float)N_NODES;
#pragma unroll
  for (int r = 0; r < NREL; ++r) {
    atomicAdd(&mv[r * HID + lane * 2], accv[r][0] * inv);
    atomicAdd(&mv[r * HID + lane * 2 + 1], accv[r][1] * inv);
  }
}

// ---------------- final: out_c = sum_rk mv[rk]*u[rk][c] + bias2@Wc + bc ----------------
__global__ __launch_bounds__(256) void k_final(const float* __restrict__ mv,
                                               const float* __restrict__ u,
                                               const float* __restrict__ bias2,
                                               const float* __restrict__ Wc,
                                               const float* __restrict__ bc,
                                               float* __restrict__ out) {
  __shared__ float r0[256], r1[256];
  const int t = threadIdx.x;
  float s0 = 0.f, s1 = 0.f;
  for (int rk = t; rk < NREL * HID; rk += 256) {
    const float m = mv[rk];
    s0 = fmaf(m, u[rk * 2], s0);
    s1 = fmaf(m, u[rk * 2 + 1], s1);
  }
  r0[t] = s0; r1[t] = s1;
  __syncthreads();
  for (int off = 128; off > 0; off >>= 1) {
    if (t < off) { r0[t] += r0[t + off]; r1[t] += r1[t + off]; }
    __syncthreads();
  }
  if (t == 0) {
    float t0 = bc[0], t1 = bc[1];
    for (int j = 0; j < HID; ++j) {
      const float b = bias2[j];
      t0 = fmaf(b, Wc[j * 2], t0);
      t1 = fmaf(b, Wc[j * 2 + 1], t1);
    }
    out[0] = r0[0] + t0;
    out[1] = r1[0] + t1;
  }
}

extern "C" void kernel_launch(void* const* d_in, const int* in_sizes, int n_in,
                              void* d_out, int out_size, void* d_ws, size_t ws_size,
                              hipStream_t stream) {
  (void)in_sizes; (void)n_in; (void)out_size; (void)ws_size;
  const float* x   = (const float*)d_in[0];
  const int* esrc  = (const int*)d_in[1];
  const int* edst  = (const int*)d_in[2];
  const float* W1  = (const float*)d_in[3];
  const float* b1  = (const float*)d_in[4];
  const float* W2  = (const float*)d_in[5];
  const float* b2  = (const float*)d_in[6];
  const float* Wc  = (const float*)d_in[7];
  const float* bc  = (const float*)d_in[8];
  float* out = (float*)d_out;

  char* p = (char*)d_ws;
  size_t off = 0;
  auto take = [&](size_t bytes) -> void* {
    void* q = p + off;
    off += (bytes + 255) & ~(size_t)255;
    return q;
  };
  // ---- zeroed region (contiguous, zeroed every call) ----
  int*   deg_in  = (int*)  take((size_t)RN * 4);
  int*   deg_out = (int*)  take((size_t)RN * 4);
  int*   cursor  = (int*)  take((size_t)RN * 4);
  float* coef    = (float*)take((size_t)RN * 4);
  float* mv      = (float*)take((size_t)NREL * HID * 4);
  const size_t zero_bytes = off;
  // ---- non-zeroed region ----
  float* norm_src = (float*)take((size_t)RN * 4);
  float* norm_dst = (float*)take((size_t)RN * 4);
  int*   csr_off  = (int*)  take((size_t)RN * 4);
  int2*  csr_ew   = (int2*) take((size_t)NREL * PADCAP * 8);
  int*   blockSums= (int*)  take((size_t)NREL * NB_SCAN * 4 + 256);
  unsigned short* W1T = (unsigned short*)take((size_t)NREL * FDIM * HID * 2);
  float* bias1    = (float*)take(HID * 4);
  float* bias2    = (float*)take(HID * 4);
  float* u        = (float*)take((size_t)NREL * HID * 2 * 4);
  unsigned short* h  = (unsigned short*)take((size_t)N_NODES * FDIM * 2);
  unsigned short* xb = (unsigned short*)take((size_t)N_NODES * FDIM * 2);

  const int zero_q = (int)(zero_bytes / 16);
  k_zero<<<(zero_q + 255) / 256, 256, 0, stream>>>((uint4*)d_ws, zero_q);
  k_deg<<<(RE + 255) / 256, 256, 0, stream>>>(esrc, edst, deg_out, deg_in);
  k_norm<<<(RN + 255) / 256, 256, 0, stream>>>(deg_out, deg_in, norm_src, norm_dst);
  k_xconv<<<(N_NODES * 32 + 255) / 256, 256, 0, stream>>>(x, xb);
  k_wconv<<<(NREL * FDIM * HID + 255) / 256, 256, 0, stream>>>(W1, b1, b2, W1T, bias1, bias2);
  k_u<<<NREL, 256, 0, stream>>>(W2, Wc, u);
  k_scan1<<<NREL * NB_SCAN, 1024, 0, stream>>>(deg_in, csr_off, blockSums);
  k_scan2<<<1, 768, 0, stream>>>(blockSums);
  k_scan3<<<(RN + 255) / 256, 256, 0, stream>>>(csr_off, blockSums);
  k_fill<<<(RE + 255) / 256, 256, 0, stream>>>(esrc, edst, csr_off, cursor,
                                               norm_src, norm_dst, csr_ew, coef);
  k_layer1<<<(N_NODES + 63) / 64, 256, 0, stream>>>(xb, csr_ew, csr_off, deg_in,
                                                    norm_dst, W1T, bias1, h);
  k_mv<<<(N_NODES + 255) / 256, 256, 0, stream>>>(h, coef, norm_src, mv);
  k_final<<<1, 256, 0, stream>>>(mv, u, bias2, Wc, bc, out);
}

// Round 4
// 866.435 us; speedup vs baseline: 1.8385x; 1.0316x over previous
//
#include <hip/hip_runtime.h>

#define N_NODES 100000
#define NREL 6
#define NEDGE 400000
#define FDIM 128
#define HID 128
#define PADCAP (NEDGE + 3 * N_NODES)   // 700000: padded-CSR capacity per relation

constexpr int RN = NREL * N_NODES;   // 600000
constexpr int RE = NREL * NEDGE;     // 2400000
constexpr int NB_SCAN = (N_NODES + 1023) / 1024;  // 98

typedef __attribute__((ext_vector_type(8))) short short8;
typedef __attribute__((ext_vector_type(4))) float f32x4;

__device__ __forceinline__ unsigned short f2bf(float f) {
  union { float f; unsigned int u; } v; v.f = f;
  unsigned int u = v.u;
  unsigned int r = (u + 0x7FFFu + ((u >> 16) & 1u)) >> 16;
  return (unsigned short)r;
}
__device__ __forceinline__ float bflo(unsigned int w) {
  union { unsigned int u; float f; } v; v.u = w << 16; return v.f;
}
__device__ __forceinline__ float bfhi(unsigned int w) {
  union { unsigned int u; float f; } v; v.u = w & 0xffff0000u; return v.f;
}

// ---------------- zero workspace (uint4 stores) ----------------
__global__ void k_zero(uint4* __restrict__ p, int nq) {
  int id = blockIdx.x * blockDim.x + threadIdx.x;
  if (id < nq) p[id] = (uint4){0u, 0u, 0u, 0u};
}

// ---------------- degree histograms: 4 edges/thread ----------------
__global__ void k_deg(const int4* __restrict__ src4, const int4* __restrict__ dst4,
                      int* __restrict__ deg_out, int* __restrict__ deg_in) {
  int id = blockIdx.x * 256 + threadIdx.x;
  if (id < RE / 4) {
    int r = id / (NEDGE / 4);
    int rN = r * N_NODES;
    int4 s = src4[id];
    int4 d = dst4[id];
    atomicAdd(&deg_out[rN + s.x], 1);
    atomicAdd(&deg_out[rN + s.y], 1);
    atomicAdd(&deg_out[rN + s.z], 1);
    atomicAdd(&deg_out[rN + s.w], 1);
    atomicAdd(&deg_in[rN + d.x], 1);
    atomicAdd(&deg_in[rN + d.y], 1);
    atomicAdd(&deg_in[rN + d.z], 1);
    atomicAdd(&deg_in[rN + d.w], 1);
  }
}

// ---------------- norms ----------------
__global__ void k_norm(const int* __restrict__ deg_out, const int* __restrict__ deg_in,
                       float* __restrict__ norm_src, float* __restrict__ norm_dst) {
  int id = blockIdx.x * 256 + threadIdx.x;
  if (id < RN) {
    int dO = deg_out[id];
    int dI = deg_in[id];
    norm_src[id] = dO > 0 ? rsqrtf((float)dO) : 0.f;
    norm_dst[id] = dI > 0 ? rsqrtf((float)dI) : 0.f;
  }
}

// ---------------- x fp32 -> bf16 ----------------
__global__ void k_xconv(const float* __restrict__ x, unsigned short* __restrict__ xb) {
  int id = blockIdx.x * 256 + threadIdx.x;
  if (id < N_NODES * 32) {
    const float4 v = ((const float4*)x)[id];
    ushort4 o;
    o.x = f2bf(v.x); o.y = f2bf(v.y); o.z = f2bf(v.z); o.w = f2bf(v.w);
    ((ushort4*)xb)[id] = o;
  }
}

// ---------------- W1 transpose+bf16 convert, bias sums ----------------
__global__ void k_wconv(const float* __restrict__ W1, const float* __restrict__ b1,
                        const float* __restrict__ b2,
                        unsigned short* __restrict__ W1T,
                        float* __restrict__ bias1, float* __restrict__ bias2) {
  int id = blockIdx.x * 256 + threadIdx.x;
  if (id < NREL * FDIM * HID) {
    int r = id >> 14;
    int rem = id & 16383;
    int j = rem >> 7;      // output feature
    int k = rem & 127;     // input feature
    W1T[id] = f2bf(W1[r * 16384 + k * 128 + j]);  // W1T[r][j][k] = W1[r][k][j]
  }
  if (id < HID) {
    float s1 = 0.f, s2 = 0.f;
    for (int r = 0; r < NREL; ++r) {
      s1 += b1[r * HID + id];
      s2 += b2[r * HID + id];
    }
    bias1[id] = s1;
    bias2[id] = s2;
  }
}

// ---------------- u[r][k][c] = sum_j W2[r][k][j] * Wc[j][c] ----------------
__global__ void k_u(const float* __restrict__ W2, const float* __restrict__ Wc,
                    float* __restrict__ u) {
  const int r = blockIdx.x;
  const int k = threadIdx.x >> 1;
  const int c = threadIdx.x & 1;
  const float* __restrict__ row = W2 + r * (HID * HID) + k * HID;
  float s = 0.f;
#pragma unroll 8
  for (int j = 0; j < HID; ++j) s = fmaf(row[j], Wc[j * 2 + c], s);
  u[(r * HID + k) * 2 + c] = s;
}

// ---------------- scan stage 1: padded degrees, per-1024 block ----------------
__global__ __launch_bounds__(1024) void k_scan1(const int* __restrict__ deg_in,
                                                int* __restrict__ csr_off,
                                                int* __restrict__ blockSums) {
  __shared__ int ws[16];
  const int r = blockIdx.x / NB_SCAN;
  const int b = blockIdx.x % NB_SCAN;
  const int t = threadIdx.x;
  const int wid = t >> 6;
  const int lane = t & 63;
  const int n = b * 1024 + t;
  const int v = (n < N_NODES) ? ((deg_in[r * N_NODES + n] + 3) & ~3) : 0;
  int sum = v;
#pragma unroll
  for (int off = 1; off < 64; off <<= 1) {
    int y = __shfl_up(sum, off);
    if (lane >= off) sum += y;
  }
  if (lane == 63) ws[wid] = sum;
  __syncthreads();
  if (wid == 0) {
    int s2 = (lane < 16) ? ws[lane] : 0;
#pragma unroll
    for (int off = 1; off < 16; off <<= 1) {
      int y = __shfl_up(s2, off);
      if (lane >= off) s2 += y;
    }
    if (lane < 16) ws[lane] = s2;
  }
  __syncthreads();
  if (wid > 0) sum += ws[wid - 1];
  if (n < N_NODES) csr_off[r * N_NODES + n] = sum - v;  // exclusive (within block)
  if (t == 1023) blockSums[blockIdx.x] = sum;
}

// ---------------- scan stage 2: exclusive scan of 98 block sums per relation ----------------
__global__ __launch_bounds__(768) void k_scan2(int* __restrict__ blockSums) {
  __shared__ int sh[NREL][128];
  const int t = threadIdx.x;
  const int r = t >> 7;
  const int b = t & 127;
  const int v = (b < NB_SCAN) ? blockSums[r * NB_SCAN + b] : 0;
  int cur = v;
  sh[r][b] = cur;
  __syncthreads();
  for (int off = 1; off < 128; off <<= 1) {
    int y = (b >= off) ? sh[r][b - off] : 0;
    __syncthreads();
    cur += y;
    sh[r][b] = cur;
    __syncthreads();
  }
  if (b < NB_SCAN) blockSums[r * NB_SCAN + b] = cur - v;  // exclusive
}

// ---------------- scan stage 3: finalize offsets; build meta + cursor ----------------
__global__ void k_scan3(const int* __restrict__ csr_off, const int* __restrict__ blockSums,
                        const int* __restrict__ deg_in, const float* __restrict__ norm_dst,
                        int* __restrict__ cursor, int4* __restrict__ meta) {
  int id = blockIdx.x * 256 + threadIdx.x;
  if (id < RN) {
    int r = id / N_NODES;
    int n = id - r * N_NODES;
    const int off = csr_off[id] + blockSums[r * NB_SCAN + (n >> 10)];
    cursor[id] = off;  // absolute write position for k_fill
    meta[id] = make_int4(deg_in[id], off, __float_as_int(norm_dst[id]), 0);
  }
}

// ---------------- CSR fill: 4 edges/thread, absolute cursor, fused coef ----------------
__global__ void k_fill(const int4* __restrict__ src4, const int4* __restrict__ dst4,
                       int* __restrict__ cursor,
                       const float* __restrict__ norm_src, const float* __restrict__ norm_dst,
                       int2* __restrict__ csr_ew, float* __restrict__ coef) {
  int id = blockIdx.x * 256 + threadIdx.x;
  if (id < RE / 4) {
    int r = id / (NEDGE / 4);
    int rN = r * N_NODES;
    int4 s = src4[id];
    int4 d = dst4[id];
    int2* __restrict__ rel = csr_ew + (size_t)r * PADCAP;
    {
      int p = atomicAdd(&cursor[rN + d.x], 1);
      atomicAdd(&coef[rN + s.x], norm_dst[rN + d.x]);
      rel[p] = make_int2(s.x, __float_as_int(norm_src[rN + s.x]));
    }
    {
      int p = atomicAdd(&cursor[rN + d.y], 1);
      atomicAdd(&coef[rN + s.y], norm_dst[rN + d.y]);
      rel[p] = make_int2(s.y, __float_as_int(norm_src[rN + s.y]));
    }
    {
      int p = atomicAdd(&cursor[rN + d.z], 1);
      atomicAdd(&coef[rN + s.z], norm_dst[rN + d.z]);
      rel[p] = make_int2(s.z, __float_as_int(norm_src[rN + s.z]));
    }
    {
      int p = atomicAdd(&cursor[rN + d.w], 1);
      atomicAdd(&coef[rN + s.w], norm_dst[rN + d.w]);
      rel[p] = make_int2(s.w, __float_as_int(norm_src[rN + s.w]));
    }
  }
}

// ---------------- fused layer-1: 32-node blocks, 2 rows/sub interleaved, MFMA ----------------
__global__ __launch_bounds__(256, 4) void k_layer1(
    const unsigned short* __restrict__ xb,   // [N][128] bf16
    const int2* __restrict__ csr_ew,         // [R][PADCAP] {src, norm_src bits}
    const int4* __restrict__ meta,           // [R][N] {deg, off, nd_bits, -}
    const unsigned short* __restrict__ W1T,  // [R][128][128] bf16 (out_feat, in_feat)
    const float* __restrict__ bias1,
    unsigned short* __restrict__ h)          // [N][128] bf16
{
  __shared__ unsigned short zA[32][136];     // 8.7 KB
  const int tid = threadIdx.x;
  const int wave = tid >> 6;
  const int lane = tid & 63;
  const int sub = lane >> 4;        // 4 subs of 16 lanes
  const int flane = lane & 15;      // 8 bf16 features per lane
  const int nodeBase = blockIdx.x * 32;   // grid is exact: 3125*32 == N_NODES

  f32x4 acc[4];
#pragma unroll
  for (int t = 0; t < 4; ++t) acc[t] = (f32x4){0.f, 0.f, 0.f, 0.f};

  // preload meta for r=0 (lanes 0..7 hold this wave's 8 rows)
  int4 mt;
  {
    const int pn = nodeBase + wave * 8 + (lane & 7);
    mt = meta[pn];  // r=0
  }

  for (int r = 0; r < NREL; ++r) {
    // distribute meta: sub handles rows wave*8+sub (row0) and wave*8+4+sub (row1)
    const int d0 = __shfl(mt.x, sub);
    const int o0 = __shfl(mt.y, sub);
    const float nd0 = __int_as_float(__shfl(mt.z, sub));
    const int d1 = __shfl(mt.x, 4 + sub);
    const int o1 = __shfl(mt.y, 4 + sub);
    const float nd1 = __int_as_float(__shfl(mt.z, 4 + sub));
    __syncthreads();  // zA free for reuse (prev MFMA done)

    const int2* __restrict__ rel = csr_ew + (size_t)r * PADCAP;
    const uint4* __restrict__ l0 = (const uint4*)(rel + o0);
    const uint4* __restrict__ l1 = (const uint4*)(rel + o1);
    const unsigned fo = (unsigned)(flane << 3);
    float b0[8], b1v[8];
#pragma unroll
    for (int k = 0; k < 8; ++k) { b0[k] = 0.f; b1v[k] = 0.f; }
    const int dmax = d0 > d1 ? d0 : d1;
    const int nb = (dmax + 3) >> 2;
    for (int bi = 0; bi < nb; ++bi) {
      const int e = bi * 4;
      const uint4 qa = l0[2 * bi], qb = l0[2 * bi + 1];
      const uint4 qc = l1[2 * bi], qd = l1[2 * bi + 1];
      // row0 edges
      const float w00 = (e < d0)     ? __int_as_float((int)qa.y) : 0.f;
      const float w01 = (e + 1 < d0) ? __int_as_float((int)qa.w) : 0.f;
      const float w02 = (e + 2 < d0) ? __int_as_float((int)qb.y) : 0.f;
      const float w03 = (e + 3 < d0) ? __int_as_float((int)qb.w) : 0.f;
      const unsigned s00 = (qa.x < (unsigned)N_NODES) ? qa.x : 0u;
      const unsigned s01 = (qa.z < (unsigned)N_NODES) ? qa.z : 0u;
      const unsigned s02 = (qb.x < (unsigned)N_NODES) ? qb.x : 0u;
      const unsigned s03 = (qb.z < (unsigned)N_NODES) ? qb.z : 0u;
      // row1 edges
      const float w10 = (e < d1)     ? __int_as_float((int)qc.y) : 0.f;
      const float w11 = (e + 1 < d1) ? __int_as_float((int)qc.w) : 0.f;
      const float w12 = (e + 2 < d1) ? __int_as_float((int)qd.y) : 0.f;
      const float w13 = (e + 3 < d1) ? __int_as_float((int)qd.w) : 0.f;
      const unsigned s10 = (qc.x < (unsigned)N_NODES) ? qc.x : 0u;
      const unsigned s11 = (qc.z < (unsigned)N_NODES) ? qc.z : 0u;
      const unsigned s12 = (qd.x < (unsigned)N_NODES) ? qd.x : 0u;
      const unsigned s13 = (qd.z < (unsigned)N_NODES) ? qd.z : 0u;
      // 8 independent gathers in flight
      const uint4 v00 = *(const uint4*)(xb + (s00 << 7) + fo);
      const uint4 v01 = *(const uint4*)(xb + (s01 << 7) + fo);
      const uint4 v02 = *(const uint4*)(xb + (s02 << 7) + fo);
      const uint4 v03 = *(const uint4*)(xb + (s03 << 7) + fo);
      const uint4 v10 = *(const uint4*)(xb + (s10 << 7) + fo);
      const uint4 v11 = *(const uint4*)(xb + (s11 << 7) + fo);
      const uint4 v12 = *(const uint4*)(xb + (s12 << 7) + fo);
      const uint4 v13 = *(const uint4*)(xb + (s13 << 7) + fo);
#define ACC8(B, V, W) \
      B[0] = fmaf(bflo(V.x), W, B[0]); B[1] = fmaf(bfhi(V.x), W, B[1]); \
      B[2] = fmaf(bflo(V.y), W, B[2]); B[3] = fmaf(bfhi(V.y), W, B[3]); \
      B[4] = fmaf(bflo(V.z), W, B[4]); B[5] = fmaf(bfhi(V.z), W, B[5]); \
      B[6] = fmaf(bflo(V.w), W, B[6]); B[7] = fmaf(bfhi(V.w), W, B[7]);
      ACC8(b0, v00, w00) ACC8(b0, v01, w01) ACC8(b0, v02, w02) ACC8(b0, v03, w03)
      ACC8(b1v, v10, w10) ACC8(b1v, v11, w11) ACC8(b1v, v12, w12) ACC8(b1v, v13, w13)
#undef ACC8
    }
    {
      uint4 pk;
      pk.x = (unsigned)f2bf(b0[0] * nd0) | ((unsigned)f2bf(b0[1] * nd0) << 16);
      pk.y = (unsigned)f2bf(b0[2] * nd0) | ((unsigned)f2bf(b0[3] * nd0) << 16);
      pk.z = (unsigned)f2bf(b0[4] * nd0) | ((unsigned)f2bf(b0[5] * nd0) << 16);
      pk.w = (unsigned)f2bf(b0[6] * nd0) | ((unsigned)f2bf(b0[7] * nd0) << 16);
      *(uint4*)(&zA[wave * 8 + sub][flane * 8]) = pk;
      pk.x = (unsigned)f2bf(b1v[0] * nd1) | ((unsigned)f2bf(b1v[1] * nd1) << 16);
      pk.y = (unsigned)f2bf(b1v[2] * nd1) | ((unsigned)f2bf(b1v[3] * nd1) << 16);
      pk.z = (unsigned)f2bf(b1v[4] * nd1) | ((unsigned)f2bf(b1v[5] * nd1) << 16);
      pk.w = (unsigned)f2bf(b1v[6] * nd1) | ((unsigned)f2bf(b1v[7] * nd1) << 16);
      *(uint4*)(&zA[wave * 8 + 4 + sub][flane * 8]) = pk;
    }
    // prefetch next relation's meta; latency hides under barrier + MFMA
    if (r + 1 < NREL) {
      const int pn = nodeBase + wave * 8 + (lane & 7);
      if (lane < 8) mt = meta[(r + 1) * N_NODES + pn];
    }
    __syncthreads();
    // ---- MFMA: 2 row-tiles x 8 col-tiles split over 4 waves
    const int rt = wave >> 1;        // row-tile
    const int ch = wave & 1;         // column half
    const int m = lane & 15;
    const int q = lane >> 4;
    const unsigned short* __restrict__ wr = W1T + r * (FDIM * HID);
#pragma unroll
    for (int kk = 0; kk < 4; ++kk) {
      const short8 af = *(const short8*)(&zA[rt * 16 + m][kk * 32 + q * 8]);
#pragma unroll
      for (int t = 0; t < 4; ++t) {
        const int ct = ch * 4 + t;
        const short8 bfr = *(const short8*)(wr + (ct * 16 + m) * 128 + kk * 32 + q * 8);
        acc[t] = __builtin_amdgcn_mfma_f32_16x16x32_bf16(af, bfr, acc[t], 0, 0, 0);
      }
    }
  }
  // ---- epilogue: bias + relu, store bf16
  const int rt = wave >> 1;
  const int ch = wave & 1;
  const int col = lane & 15;
  const int rq = (lane >> 4) * 4;
#pragma unroll
  for (int t = 0; t < 4; ++t) {
#pragma unroll
    for (int rr = 0; rr < 4; ++rr) {
      const int node = nodeBase + rt * 16 + rq + rr;
      const int f = (ch * 4 + t) * 16 + col;
      float v = acc[t][rr] + bias1[f];
      v = fmaxf(v, 0.f);
      h[(size_t)node * FDIM + f] = f2bf(v);
    }
  }
}

// ---------------- layer-2 folded: mv[r] = (1/N) sum_n cc_r[n] * h[n] ----------------
__global__ __launch_bounds__(256) void k_mv(const unsigned short* __restrict__ h,
                                            const float* __restrict__ coef,
                                            const float* __restrict__ norm_src,
                                            float* __restrict__ mv) {
  const int wave = threadIdx.x >> 6;
  const int lane = threadIdx.x & 63;
  const int base = blockIdx.x * 256 + wave * 64;
  float ccP[NREL];
  const int pn = base + lane;
#pragma unroll
  for (int r = 0; r < NREL; ++r) {
    ccP[r] = (pn < N_NODES) ? coef[r * N_NODES + pn] * norm_src[r * N_NODES + pn] : 0.f;
  }
  float accv[NREL][2];
#pragma unroll
  for (int r = 0; r < NREL; ++r) { accv[r][0] = 0.f; accv[r][1] = 0.f; }
  if (base < N_NODES) {
    const int lim = min(64, N_NODES - base);
    for (int i = 0; i < lim; ++i) {
      const unsigned int hv = *(const unsigned int*)(h + (size_t)(base + i) * FDIM + lane * 2);
      const float h0 = bflo(hv);
      const float h1 = bfhi(hv);
#pragma unroll
      for (int r = 0; r < NREL; ++r) {
        const float c = __shfl(ccP[r], i);
        accv[r][0] = fmaf(c, h0, accv[r][0]);
        accv[r][1] = fmaf(c, h1, accv[r][1]);
      }
    }
  }
  const float inv = 1.0f / (float)N_NODES;
#pragma unroll
  for (int r = 0; r < NREL; ++r) {
    atomicAdd(&mv[r * HID + lane * 2], accv[r][0] * inv);
    atomicAdd(&mv[r * HID + lane * 2 + 1], accv[r][1] * inv);
  }
}

// ---------------- final: out_c = sum_rk mv[rk]*u[rk][c] + bias2@Wc + bc ----------------
__global__ __launch_bounds__(256) void k_final(const float* __restrict__ mv,
                                               const float* __restrict__ u,
                                               const float* __restrict__ bias2,
                                               const float* __restrict__ Wc,
                                               const float* __restrict__ bc,
                                               float* __restrict__ out) {
  __shared__ float r0[256], r1[256];
  const int t = threadIdx.x;
  float s0 = 0.f, s1 = 0.f;
  for (int rk = t; rk < NREL * HID; rk += 256) {
    const float m = mv[rk];
    s0 = fmaf(m, u[rk * 2], s0);
    s1 = fmaf(m, u[rk * 2 + 1], s1);
  }
  r0[t] = s0; r1[t] = s1;
  __syncthreads();
  for (int off = 128; off > 0; off >>= 1) {
    if (t < off) { r0[t] += r0[t + off]; r1[t] += r1[t + off]; }
    __syncthreads();
  }
  if (t == 0) {
    float t0 = bc[0], t1 = bc[1];
    for (int j = 0; j < HID; ++j) {
      const float b = bias2[j];
      t0 = fmaf(b, Wc[j * 2], t0);
      t1 = fmaf(b, Wc[j * 2 + 1], t1);
    }
    out[0] = r0[0] + t0;
    out[1] = r1[0] + t1;
  }
}

extern "C" void kernel_launch(void* const* d_in, const int* in_sizes, int n_in,
                              void* d_out, int out_size, void* d_ws, size_t ws_size,
                              hipStream_t stream) {
  (void)in_sizes; (void)n_in; (void)out_size; (void)ws_size;
  const float* x   = (const float*)d_in[0];
  const int* esrc  = (const int*)d_in[1];
  const int* edst  = (const int*)d_in[2];
  const float* W1  = (const float*)d_in[3];
  const float* b1  = (const float*)d_in[4];
  const float* W2  = (const float*)d_in[5];
  const float* b2  = (const float*)d_in[6];
  const float* Wc  = (const float*)d_in[7];
  const float* bc  = (const float*)d_in[8];
  float* out = (float*)d_out;

  char* p = (char*)d_ws;
  size_t off = 0;
  auto take = [&](size_t bytes) -> void* {
    void* q = p + off;
    off += (bytes + 255) & ~(size_t)255;
    return q;
  };
  // ---- zeroed region (contiguous, zeroed every call) ----
  int*   deg_in  = (int*)  take((size_t)RN * 4);
  int*   deg_out = (int*)  take((size_t)RN * 4);
  float* coef    = (float*)take((size_t)RN * 4);
  float* mv      = (float*)take((size_t)NREL * HID * 4);
  const size_t zero_bytes = off;
  // ---- non-zeroed region ----
  int*   cursor   = (int*)  take((size_t)RN * 4);
  float* norm_src = (float*)take((size_t)RN * 4);
  float* norm_dst = (float*)take((size_t)RN * 4);
  int*   csr_off  = (int*)  take((size_t)RN * 4);
  int4*  meta     = (int4*) take((size_t)RN * 16);
  int2*  csr_ew   = (int2*) take((size_t)NREL * PADCAP * 8);
  int*   blockSums= (int*)  take((size_t)NREL * NB_SCAN * 4 + 256);
  unsigned short* W1T = (unsigned short*)take((size_t)NREL * FDIM * HID * 2);
  float* bias1    = (float*)take(HID * 4);
  float* bias2    = (float*)take(HID * 4);
  float* u        = (float*)take((size_t)NREL * HID * 2 * 4);
  unsigned short* h  = (unsigned short*)take((size_t)N_NODES * FDIM * 2);
  unsigned short* xb = (unsigned short*)take((size_t)N_NODES * FDIM * 2);

  const int zero_q = (int)(zero_bytes / 16);
  k_zero<<<(zero_q + 255) / 256, 256, 0, stream>>>((uint4*)d_ws, zero_q);
  k_deg<<<(RE / 4 + 255) / 256, 256, 0, stream>>>((const int4*)esrc, (const int4*)edst,
                                                  deg_out, deg_in);
  k_norm<<<(RN + 255) / 256, 256, 0, stream>>>(deg_out, deg_in, norm_src, norm_dst);
  k_xconv<<<(N_NODES * 32 + 255) / 256, 256, 0, stream>>>(x, xb);
  k_wconv<<<(NREL * FDIM * HID + 255) / 256, 256, 0, stream>>>(W1, b1, b2, W1T, bias1, bias2);
  k_u<<<NREL, 256, 0, stream>>>(W2, Wc, u);
  k_scan1<<<NREL * NB_SCAN, 1024, 0, stream>>>(deg_in, csr_off, blockSums);
  k_scan2<<<1, 768, 0, stream>>>(blockSums);
  k_scan3<<<(RN + 255) / 256, 256, 0, stream>>>(csr_off, blockSums, deg_in, norm_dst,
                                                cursor, meta);
  k_fill<<<(RE / 4 + 255) / 256, 256, 0, stream>>>((const int4*)esrc, (const int4*)edst,
                                                   cursor, norm_src, norm_dst, csr_ew, coef);
  k_layer1<<<N_NODES / 32, 256, 0, stream>>>(xb, csr_ew, meta, W1T, bias1, h);
  k_mv<<<(N_NODES + 255) / 256, 256, 0, stream>>>(h, coef, norm_src, mv);
  k_final<<<1, 256, 0, stream>>>(mv, u, bias2, Wc, bc, out);
}